// Round 20
// baseline (922.464 us; speedup 1.0000x reference)
//
#include <hip/hip_runtime.h>
#include <stdint.h>
#include <math.h>

#define NE 8
#define NT 8192
#define NH 1024
#define NI 4096
#define BM 128
#define BK 32

typedef _Float16 half8 __attribute__((ext_vector_type(8)));
typedef float f32x4 __attribute__((ext_vector_type(4)));

// ---------------- workspace layout ----------------
// ints at base: [0..8) cnt  [8..17) off  [17..25) cursor  [25..34) mbcum(128)
// int 64..            : te[NT*2]
// int 64+NT*2         : tw[NT*2] (float)
// int 64+NT*4         : tok_slot[NT*2]
// int 64+NT*6         : w_slot[NT*2] (float)
// int 64+NT*8         : islot[NT*2]
// byte 0.5MiB : x16   (16 MiB)
// byte 18MiB  : act   (128 MiB)
// byte 146MiB : gup16 (128 MiB) — after gemm1: y0 (64 MiB) + y1 (64 MiB) (R20)
// byte 274MiB : dp16  (64 MiB)  -> ends 338 MiB (fits, proven R2-R19)
#define OFF_X16   (512u << 10)
#define OFF_ACT   (18u << 20)
#define OFF_GUP16 (146ull << 20)
#define OFF_DP16  (274ull << 20)

__device__ __forceinline__ half8 pack_half8v(f32x4 a, f32x4 b) {
  half8 h;
  h[0] = (_Float16)a[0]; h[1] = (_Float16)a[1]; h[2] = (_Float16)a[2]; h[3] = (_Float16)a[3];
  h[4] = (_Float16)b[0]; h[5] = (_Float16)b[1]; h[6] = (_Float16)b[2]; h[7] = (_Float16)b[3];
  return h;
}

__device__ __forceinline__ void gload16(const void* g, void* l) {
  __builtin_amdgcn_global_load_lds(
      (const __attribute__((address_space(1))) uint32_t*)g,
      (__attribute__((address_space(3))) uint32_t*)l, 16, 0, 0);
}

// counted-vmcnt pipeline primitives (T4): raw barrier, NO compiler drain.
// RULE (R8): every tile-top PIPE_WAIT must be followed by PIPE_BAR before any
// ds_read of staged data. R17: 3-stage/48KB = 3 blocks/CU sweet spot.
#define PIPE_WAIT(N) asm volatile("s_waitcnt vmcnt(" #N ")" ::: "memory")
#define PIPE_BAR() do { asm volatile("" ::: "memory"); \
                        __builtin_amdgcn_s_barrier(); \
                        asm volatile("" ::: "memory"); } while (0)

// ======== kernel A: router (2048 blocks) + gup convert (4096 blocks) =====
__global__ __launch_bounds__(256) void conv_router(
    const float* __restrict__ x, const float* __restrict__ rw,
    int* __restrict__ iws, _Float16* __restrict__ x16,
    const float* __restrict__ gup, _Float16* __restrict__ gup16)
{
  int bid = blockIdx.x;
  if (bid >= 2048) {
    int cbid = bid - 2048;
    const int n8g = NE*2*NI*NH/8;
    int stride = 4096 * 256;
    for (int i = cbid * 256 + threadIdx.x; i < n8g; i += stride) {
      const f32x4* p = (const f32x4*)(gup + (size_t)i * 8);
      f32x4 a = __builtin_nontemporal_load(p);
      f32x4 b = __builtin_nontemporal_load(p + 1);
      *(half8*)(gup16 + (size_t)i * 8) = pack_half8v(a, b);
    }
    return;
  }
  int wid  = threadIdx.x >> 6;
  int lane = threadIdx.x & 63;
  int t = (bid << 2) + wid;

  const float4* xp4 = (const float4*)(x + (size_t)t * NH + lane * 16);
  float xv[16];
  #pragma unroll
  for (int j = 0; j < 4; ++j) {
    float4 v = xp4[j];
    xv[4*j+0] = v.x; xv[4*j+1] = v.y; xv[4*j+2] = v.z; xv[4*j+3] = v.w;
  }
  half8 h0, h1;
  #pragma unroll
  for (int j = 0; j < 8; ++j) { h0[j] = (_Float16)xv[j]; h1[j] = (_Float16)xv[8+j]; }
  half8* xo = (half8*)(x16 + (size_t)t * NH + lane * 16);
  xo[0] = h0; xo[1] = h1;

  float lg[NE];
  #pragma unroll
  for (int e = 0; e < NE; ++e) {
    const float4* wp4 = (const float4*)(rw + e * NH + lane * 16);
    float s = 0.f;
    #pragma unroll
    for (int j = 0; j < 4; ++j) {
      float4 w = wp4[j];
      s += xv[4*j+0]*w.x + xv[4*j+1]*w.y + xv[4*j+2]*w.z + xv[4*j+3]*w.w;
    }
    lg[e] = s;
  }
  #pragma unroll
  for (int d = 32; d > 0; d >>= 1) {
    #pragma unroll
    for (int e = 0; e < NE; ++e) lg[e] += __shfl_xor(lg[e], d, 64);
  }
  if (lane == 0) {
    int e0 = 0;
    #pragma unroll
    for (int e = 1; e < NE; ++e) if (lg[e] > lg[e0]) e0 = e;
    int e1 = (e0 == 0) ? 1 : 0;
    #pragma unroll
    for (int e = 0; e < NE; ++e) if (e != e0 && lg[e] > lg[e1]) e1 = e;
    float p1 = expf(lg[e1] - lg[e0]);
    float s  = 1.f + p1;
    int*   te = iws + 64;
    float* tw = (float*)(iws + 64 + NT*2);
    te[2*t]   = e0; te[2*t+1] = e1;
    tw[2*t]   = 1.f / s; tw[2*t+1] = p1 / s;
    atomicAdd(iws + e0, 1);
    atomicAdd(iws + e1, 1);
  }
}

// ---------------- scan ----------------
__global__ void moe_scan(int* iws) {
  if (threadIdx.x == 0 && blockIdx.x == 0) {
    int* cnt = iws; int* off = iws + 8; int* mbc = iws + 25;
    int o = 0, m = 0;
    for (int e = 0; e < NE; ++e) {
      off[e] = o; mbc[e] = m;
      o += cnt[e];
      m += (cnt[e] + BM - 1) / BM;
    }
    off[NE] = o; mbc[NE] = m;
  }
}

// ---------------- fill slot lists (+ token->slot map) ----------------
__global__ __launch_bounds__(256) void moe_fill(int* __restrict__ iws) {
  int t = blockIdx.x * 256 + threadIdx.x;
  const int*   te = iws + 64;
  const float* tw = (const float*)(iws + 64 + NT*2);
  int*   cursor   = iws + 17;
  const int* off  = iws + 8;
  int*   tok_slot = iws + 64 + NT*4;
  float* w_slot   = (float*)(iws + 64 + NT*6);
  int*   islot    = iws + 64 + NT*8;
  #pragma unroll
  for (int k = 0; k < 2; ++k) {
    int e = te[2*t+k];
    int pos = atomicAdd(&cursor[e], 1);
    int s = off[e] + pos;
    tok_slot[s] = t;
    w_slot[s]   = tw[2*t+k];
    islot[2*t+k] = s;
  }
}

// ======== kernel B: gemm1 (8704 blocks) + dp-convert riders (1088) ======
__global__ __launch_bounds__(256, 2) void moe_gemm1_f16(
    const _Float16* __restrict__ x16, const _Float16* __restrict__ gup16,
    const int* __restrict__ iws, _Float16* __restrict__ act,
    const float* __restrict__ dp, _Float16* __restrict__ dp16)
{
  int bidr = blockIdx.x;
  int grp = bidr / 9, rem = bidr - grp * 9;
  if (rem == 8) {
    const int n8d = NE*NH*NI/8;
    int stride = 1088 * 256;
    for (int i = grp * 256 + threadIdx.x; i < n8d; i += stride) {
      const f32x4* p = (const f32x4*)(dp + (size_t)i * 8);
      f32x4 a = __builtin_nontemporal_load(p);
      f32x4 b = __builtin_nontemporal_load(p + 1);
      *(half8*)(dp16 + (size_t)i * 8) = pack_half8v(a, b);
    }
    return;
  }
  int bid = grp * 8 + rem;       // 0..8703

  const int* cnt = iws; const int* off = iws + 8; const int* mbc = iws + 25;
  const int* tok_slot = iws + 64 + NT*4;
  int mb  = bid >> 6;
  int i0  = (bid & 63) << 6;
  if (mb >= mbc[NE]) return;
  int e = 0;
  while (mb >= mbc[e+1]) ++e;
  int mloc  = mb - mbc[e];
  int row0  = off[e] + mloc * BM;
  int nrows = cnt[e] - mloc * BM; if (nrows > BM) nrows = BM;

  __shared__ __align__(16) _Float16 Al [3][BM * BK];
  __shared__ __align__(16) _Float16 Bgl[3][64 * BK];
  __shared__ __align__(16) _Float16 Bul[3][64 * BK];   // 48 KB -> 3 blocks/CU

  int tid = threadIdx.x, wid = tid >> 6, lane = tid & 63;
  int sr0 = wid*16 + (lane >> 2);
  int sr1 = 64 + sr0;
  int slot = lane & 3;
  int ks0 = (slot ^ ((sr0 >> 1) & 3)) * 8;
  int ks1 = (slot ^ ((sr1 >> 1) & 3)) * 8;

  int tok0 = tok_slot[row0 + (sr0 < nrows ? sr0 : 0)];
  int tok1 = tok_slot[row0 + (sr1 < nrows ? sr1 : 0)];
  const _Float16* pA0 = x16 + (size_t)tok0 * NH + ks0;
  const _Float16* pA1 = x16 + (size_t)tok1 * NH + ks1;
  const _Float16* pBg = gup16 + ((size_t)e*2*NI + i0 + sr0) * NH + ks0;
  const _Float16* pBu = pBg + (size_t)NI * NH;

  int wr = (wid >> 1) * 64, wc = (wid & 1) * 32;
  int fr = lane & 15, fq = lane >> 4;

  f32x4 accG[4][2] = {};
  f32x4 accU[4][2] = {};

  _Float16 *A0 = &Al[0][0], *A1 = &Al[1][0], *A2 = &Al[2][0];
  _Float16 *G0 = &Bgl[0][0], *G1 = &Bgl[1][0], *G2 = &Bgl[2][0];
  _Float16 *U0 = &Bul[0][0], *U1 = &Bul[1][0], *U2 = &Bul[2][0];

#define STAGE1(Ab, Gb, Ub, kk) do { \
    gload16(pA0 + (kk), (Ab) + wid*512); \
    gload16(pA1 + (kk), (Ab) + (4+wid)*512); \
    gload16(pBg + (kk), (Gb) + wid*512); \
    gload16(pBu + (kk), (Ub) + wid*512); \
  } while (0)

#define COMPUTE1(Ab, Gb, Ub) do { \
    half8 aF[4]; \
    _Pragma("unroll") \
    for (int m = 0; m < 4; ++m) { \
      int r = wr + m*16 + fr; \
      aF[m] = *(const half8*)((Ab) + r*BK + ((fq ^ ((r>>1)&3)) * 8)); \
    } \
    __builtin_amdgcn_s_setprio(1); \
    _Pragma("unroll") \
    for (int n = 0; n < 2; ++n) { \
      int rb = wc + n*16 + fr; \
      int bo = rb*BK + ((fq ^ ((rb>>1)&3)) * 8); \
      half8 bg = *(const half8*)((Gb) + bo); \
      half8 bu = *(const half8*)((Ub) + bo); \
      _Pragma("unroll") \
      for (int m = 0; m < 4; ++m) \
        accG[m][n] = __builtin_amdgcn_mfma_f32_16x16x32_f16(aF[m], bg, accG[m][n], 0, 0, 0); \
      _Pragma("unroll") \
      for (int m = 0; m < 4; ++m) \
        accU[m][n] = __builtin_amdgcn_mfma_f32_16x16x32_f16(aF[m], bu, accU[m][n], 0, 0, 0); \
    } \
    __builtin_amdgcn_s_setprio(0); \
  } while (0)

#define ROT1() do { _Float16* t_; \
    t_ = A0; A0 = A1; A1 = A2; A2 = t_; \
    t_ = G0; G0 = G1; G1 = G2; G2 = t_; \
    t_ = U0; U0 = U1; U1 = U2; U2 = t_; } while (0)

  STAGE1(A0, G0, U0, 0);
  STAGE1(A1, G1, U1, BK);

  for (int k0 = 0; k0 + 2*BK < NH; k0 += BK) {
    PIPE_WAIT(4);
    PIPE_BAR();
    STAGE1(A2, G2, U2, k0 + 2*BK);
    COMPUTE1(A0, G0, U0);
    ROT1();
  }
  PIPE_WAIT(4);
  PIPE_BAR();
  COMPUTE1(A0, G0, U0);
  ROT1();
  PIPE_WAIT(0);
  PIPE_BAR();
  COMPUTE1(A0, G0, U0);

#undef STAGE1
#undef COMPUTE1
#undef ROT1

  #pragma unroll
  for (int m = 0; m < 4; ++m) {
    #pragma unroll
    for (int j = 0; j < 4; ++j) {
      int rl = wr + m*16 + fq*4 + j;
      if (rl < nrows) {
        _Float16* dst = act + (size_t)(row0 + rl) * NI + i0 + wc + fr;
        #pragma unroll
        for (int n = 0; n < 2; ++n) {
          float g = accG[m][n][j], u = accU[m][n][j];
          float a = (g / (1.f + __expf(-g))) * u;
          dst[n*16] = (_Float16)a;
        }
      }
    }
  }
}

// ======== gemm2 (R20): K-split x2, non-atomic partials, 94% grid util ======
// Grid = 136 mb x 8 h x 2 ks = 2176 blocks (2.83 waves at 3 blk/CU, was 1.42).
// bid = (mb>>3)*128 + h*16 + ks*8 + (mb&7): all 16 (h,ks) slices of an mb on
// one XCD within a 128-bid window (act panel clustered, R13 mechanism).
// Each block computes K half [ks*2048, ks*2048+2048), writes y[ks] partial.
__global__ __launch_bounds__(256, 2) void moe_gemm2_f16(
    const _Float16* __restrict__ act, const _Float16* __restrict__ dp16,
    const int* __restrict__ iws, float* __restrict__ y)
{
  const int* cnt = iws; const int* off = iws + 8; const int* mbc = iws + 25;
  const float* w_slot = (const float*)(iws + 64 + NT*6);
  int bid = blockIdx.x;
  int mb  = ((bid >> 7) << 3) | (bid & 7);
  int h0  = ((bid >> 4) & 7) << 7;
  int ksl = (bid >> 3) & 1;
  int kbeg = ksl << 11;                       // 0 or 2048
  if (mb >= mbc[NE]) return;
  int e = 0;
  while (mb >= mbc[e+1]) ++e;
  int mloc  = mb - mbc[e];
  int row0  = off[e] + mloc * BM;
  int nrows = cnt[e] - mloc * BM; if (nrows > BM) nrows = BM;

  __shared__ __align__(16) _Float16 Al[3][BM  * BK];
  __shared__ __align__(16) _Float16 Bl[3][128 * BK];   // 48 KB -> 3 blocks/CU

  int tid = threadIdx.x, wid = tid >> 6, lane = tid & 63;
  int sr0 = wid*16 + (lane >> 2);
  int sr1 = 64 + sr0;
  int slot = lane & 3;
  int ks0 = (slot ^ ((sr0 >> 1) & 3)) * 8;
  int ks1 = (slot ^ ((sr1 >> 1) & 3)) * 8;

  const _Float16* pA0 = act + (size_t)(row0 + (sr0 < nrows ? sr0 : 0)) * NI + ks0;
  const _Float16* pA1 = act + (size_t)(row0 + (sr1 < nrows ? sr1 : 0)) * NI + ks1;
  const _Float16* pB0 = dp16 + ((size_t)e*NH + h0 + sr0) * NI + ks0;
  const _Float16* pB1 = dp16 + ((size_t)e*NH + h0 + sr1) * NI + ks1;

  int wr = (wid >> 1) * 64, wc = (wid & 1) * 64;
  int fr = lane & 15, fq = lane >> 4;

  f32x4 acc[4][4] = {};

  _Float16 *A0 = &Al[0][0], *A1 = &Al[1][0], *A2 = &Al[2][0];
  _Float16 *B0 = &Bl[0][0], *B1 = &Bl[1][0], *B2 = &Bl[2][0];

#define STAGE2(Ab, Bb, kk) do { \
    gload16(pA0 + (kk), (Ab) + wid*512); \
    gload16(pA1 + (kk), (Ab) + (4+wid)*512); \
    gload16(pB0 + (kk), (Bb) + wid*512); \
    gload16(pB1 + (kk), (Bb) + (4+wid)*512); \
  } while (0)

#define COMPUTE2(Ab, Bb) do { \
    half8 aF[4]; \
    _Pragma("unroll") \
    for (int m = 0; m < 4; ++m) { \
      int r = wr + m*16 + fr; \
      aF[m] = *(const half8*)((Ab) + r*BK + ((fq ^ ((r>>1)&3)) * 8)); \
    } \
    __builtin_amdgcn_s_setprio(1); \
    _Pragma("unroll") \
    for (int n = 0; n < 4; ++n) { \
      int rb = wc + n*16 + fr; \
      half8 b = *(const half8*)((Bb) + rb*BK + ((fq ^ ((rb>>1)&3)) * 8)); \
      _Pragma("unroll") \
      for (int m = 0; m < 4; ++m) \
        acc[m][n] = __builtin_amdgcn_mfma_f32_16x16x32_f16(aF[m], b, acc[m][n], 0, 0, 0); \
    } \
    __builtin_amdgcn_s_setprio(0); \
  } while (0)

#define ROT2() do { _Float16* t_; \
    t_ = A0; A0 = A1; A1 = A2; A2 = t_; \
    t_ = B0; B0 = B1; B1 = B2; B2 = t_; } while (0)

  STAGE2(A0, B0, kbeg);
  STAGE2(A1, B1, kbeg + BK);

  for (int k0 = kbeg; k0 + 2*BK < kbeg + 2048; k0 += BK) {
    PIPE_WAIT(4);
    PIPE_BAR();
    STAGE2(A2, B2, k0 + 2*BK);
    COMPUTE2(A0, B0);
    ROT2();
  }
  PIPE_WAIT(4);
  PIPE_BAR();
  COMPUTE2(A0, B0);
  ROT2();
  PIPE_WAIT(0);
  PIPE_BAR();
  COMPUTE2(A0, B0);

#undef STAGE2
#undef COMPUTE2
#undef ROT2

  // epilogue: y[ksl][slot][h0+col] = wgt * acc_half (exclusive, no atomics)
  float* yk = y + (size_t)ksl * (NT*2) * NH;
  #pragma unroll
  for (int m = 0; m < 4; ++m) {
    #pragma unroll
    for (int j = 0; j < 4; ++j) {
      int rl = wr + m*16 + fq*4 + j;
      if (rl < nrows) {
        int slotr = row0 + rl;
        float wgt = w_slot[slotr];
        float* dst = yk + (size_t)slotr * NH + h0 + wc + fr;
        #pragma unroll
        for (int n = 0; n < 4; ++n)
          dst[n*16] = acc[m][n][j] * wgt;
      }
    }
  }
}

// ======== combine: out[t] = sum over {slots} x {k-halves} of y ========
__global__ __launch_bounds__(256) void moe_combine(
    const float* __restrict__ y, const int* __restrict__ iws,
    float* __restrict__ out)
{
  const int* islot = iws + 64 + NT*8;
  const size_t YK = (size_t)(NT*2) * NH;
  int t = blockIdx.x;
  int s0 = islot[2*t], s1 = islot[2*t+1];
  const f32x4* a0 = (const f32x4*)(y + (size_t)s0 * NH);
  const f32x4* a1 = (const f32x4*)(y + (size_t)s0 * NH + YK);
  const f32x4* b0 = (const f32x4*)(y + (size_t)s1 * NH);
  const f32x4* b1 = (const f32x4*)(y + (size_t)s1 * NH + YK);
  f32x4* o = (f32x4*)(out + (size_t)t * NH);
  int i = threadIdx.x;           // 256 threads x f32x4 = 1024 elems
  o[i] = (a0[i] + a1[i]) + (b0[i] + b1[i]);
}

extern "C" void kernel_launch(void* const* d_in, const int* in_sizes, int n_in,
                              void* d_out, int out_size, void* d_ws, size_t ws_size,
                              hipStream_t stream) {
  const float* x   = (const float*)d_in[0];
  const float* rw  = (const float*)d_in[1];
  const float* gup = (const float*)d_in[2];
  const float* dp  = (const float*)d_in[3];
  float* out = (float*)d_out;
  int* iws = (int*)d_ws;
  _Float16* x16   = (_Float16*)((char*)d_ws + OFF_X16);
  _Float16* act   = (_Float16*)((char*)d_ws + OFF_ACT);
  _Float16* gup16 = (_Float16*)((char*)d_ws + OFF_GUP16);
  _Float16* dp16  = (_Float16*)((char*)d_ws + OFF_DP16);
  // y partials (2 x 64 MiB) overlay gup16's region (gemm1 done before gemm2)
  float* y = (float*)((char*)d_ws + OFF_GUP16);

  hipMemsetAsync(d_ws, 0, 512, stream);

  // A: router (2048) + gup convert (4096) fused
  conv_router<<<6144, 256, 0, stream>>>(x, rw, iws, x16, gup, gup16);
  moe_scan<<<1, 64, 0, stream>>>(iws);
  moe_fill<<<NT / 256, 256, 0, stream>>>(iws);

  // B: gemm1 (8704) + dp-convert riders (1088) interleaved every 9th bid
  moe_gemm1_f16<<<9792, 256, 0, stream>>>(x16, gup16, iws, act, dp, dp16);
  // gemm2: K-split x2, mb-window permuted grid, 136 x 8 x 2 = 2176
  moe_gemm2_f16<<<2176, 256, 0, stream>>>(act, dp16, iws, y);
  moe_combine<<<NT, 256, 0, stream>>>(y, iws, out);
}

// Round 21
// 914.284 us; speedup vs baseline: 1.0089x; 1.0089x over previous
//
#include <hip/hip_runtime.h>
#include <stdint.h>
#include <math.h>

#define NE 8
#define NT 8192
#define NH 1024
#define NI 4096
#define BM 128
#define BK 32

typedef _Float16 half8 __attribute__((ext_vector_type(8)));
typedef float f32x4 __attribute__((ext_vector_type(4)));

// ---------------- workspace layout ----------------
// ints at base: [0..8) cnt  [8..17) off  [17..25) cursor  [25..34) mbcum(128)
// int 64..            : te[NT*2]
// int 64+NT*2         : tw[NT*2] (float)
// int 64+NT*4         : tok_slot[NT*2]
// int 64+NT*6         : w_slot[NT*2] (float)
// int 64+NT*8         : islot[NT*2]
// byte 0.5MiB : x16   (16 MiB)
// byte 18MiB  : act   (128 MiB)
// byte 146MiB : gup16 (128 MiB) — after gemm1, first 64 MiB reused as y_slots
// byte 274MiB : dp16  (64 MiB)  -> ends 338 MiB (fits, proven R2-R20)
#define OFF_X16   (512u << 10)
#define OFF_ACT   (18u << 20)
#define OFF_GUP16 (146ull << 20)
#define OFF_DP16  (274ull << 20)

__device__ __forceinline__ half8 pack_half8v(f32x4 a, f32x4 b) {
  half8 h;
  h[0] = (_Float16)a[0]; h[1] = (_Float16)a[1]; h[2] = (_Float16)a[2]; h[3] = (_Float16)a[3];
  h[4] = (_Float16)b[0]; h[5] = (_Float16)b[1]; h[6] = (_Float16)b[2]; h[7] = (_Float16)b[3];
  return h;
}

__device__ __forceinline__ void gload16(const void* g, void* l) {
  __builtin_amdgcn_global_load_lds(
      (const __attribute__((address_space(1))) uint32_t*)g,
      (__attribute__((address_space(3))) uint32_t*)l, 16, 0, 0);
}

// counted-vmcnt pipeline primitives (T4): raw barrier, NO compiler drain.
// RULE (R8): every tile-top PIPE_WAIT must be followed by PIPE_BAR before any
// ds_read of staged data. R17: 3-stage/48KB = 3 blocks/CU sweet spot.
#define PIPE_WAIT(N) asm volatile("s_waitcnt vmcnt(" #N ")" ::: "memory")
#define PIPE_BAR() do { asm volatile("" ::: "memory"); \
                        __builtin_amdgcn_s_barrier(); \
                        asm volatile("" ::: "memory"); } while (0)

// ======== kernel A: router (2048 blocks) + gup convert (4096 blocks) =====
__global__ __launch_bounds__(256) void conv_router(
    const float* __restrict__ x, const float* __restrict__ rw,
    int* __restrict__ iws, _Float16* __restrict__ x16,
    const float* __restrict__ gup, _Float16* __restrict__ gup16)
{
  int bid = blockIdx.x;
  if (bid >= 2048) {
    int cbid = bid - 2048;
    const int n8g = NE*2*NI*NH/8;
    int stride = 4096 * 256;
    for (int i = cbid * 256 + threadIdx.x; i < n8g; i += stride) {
      const f32x4* p = (const f32x4*)(gup + (size_t)i * 8);
      f32x4 a = __builtin_nontemporal_load(p);
      f32x4 b = __builtin_nontemporal_load(p + 1);
      *(half8*)(gup16 + (size_t)i * 8) = pack_half8v(a, b);
    }
    return;
  }
  int wid  = threadIdx.x >> 6;
  int lane = threadIdx.x & 63;
  int t = (bid << 2) + wid;

  const float4* xp4 = (const float4*)(x + (size_t)t * NH + lane * 16);
  float xv[16];
  #pragma unroll
  for (int j = 0; j < 4; ++j) {
    float4 v = xp4[j];
    xv[4*j+0] = v.x; xv[4*j+1] = v.y; xv[4*j+2] = v.z; xv[4*j+3] = v.w;
  }
  half8 h0, h1;
  #pragma unroll
  for (int j = 0; j < 8; ++j) { h0[j] = (_Float16)xv[j]; h1[j] = (_Float16)xv[8+j]; }
  half8* xo = (half8*)(x16 + (size_t)t * NH + lane * 16);
  xo[0] = h0; xo[1] = h1;

  float lg[NE];
  #pragma unroll
  for (int e = 0; e < NE; ++e) {
    const float4* wp4 = (const float4*)(rw + e * NH + lane * 16);
    float s = 0.f;
    #pragma unroll
    for (int j = 0; j < 4; ++j) {
      float4 w = wp4[j];
      s += xv[4*j+0]*w.x + xv[4*j+1]*w.y + xv[4*j+2]*w.z + xv[4*j+3]*w.w;
    }
    lg[e] = s;
  }
  #pragma unroll
  for (int d = 32; d > 0; d >>= 1) {
    #pragma unroll
    for (int e = 0; e < NE; ++e) lg[e] += __shfl_xor(lg[e], d, 64);
  }
  if (lane == 0) {
    int e0 = 0;
    #pragma unroll
    for (int e = 1; e < NE; ++e) if (lg[e] > lg[e0]) e0 = e;
    int e1 = (e0 == 0) ? 1 : 0;
    #pragma unroll
    for (int e = 0; e < NE; ++e) if (e != e0 && lg[e] > lg[e1]) e1 = e;
    float p1 = expf(lg[e1] - lg[e0]);
    float s  = 1.f + p1;
    int*   te = iws + 64;
    float* tw = (float*)(iws + 64 + NT*2);
    te[2*t]   = e0; te[2*t+1] = e1;
    tw[2*t]   = 1.f / s; tw[2*t+1] = p1 / s;
    atomicAdd(iws + e0, 1);
    atomicAdd(iws + e1, 1);
  }
}

// ---------------- scan ----------------
__global__ void moe_scan(int* iws) {
  if (threadIdx.x == 0 && blockIdx.x == 0) {
    int* cnt = iws; int* off = iws + 8; int* mbc = iws + 25;
    int o = 0, m = 0;
    for (int e = 0; e < NE; ++e) {
      off[e] = o; mbc[e] = m;
      o += cnt[e];
      m += (cnt[e] + BM - 1) / BM;
    }
    off[NE] = o; mbc[NE] = m;
  }
}

// ---------------- fill slot lists (+ token->slot map) ----------------
__global__ __launch_bounds__(256) void moe_fill(int* __restrict__ iws) {
  int t = blockIdx.x * 256 + threadIdx.x;
  const int*   te = iws + 64;
  const float* tw = (const float*)(iws + 64 + NT*2);
  int*   cursor   = iws + 17;
  const int* off  = iws + 8;
  int*   tok_slot = iws + 64 + NT*4;
  float* w_slot   = (float*)(iws + 64 + NT*6);
  int*   islot    = iws + 64 + NT*8;
  #pragma unroll
  for (int k = 0; k < 2; ++k) {
    int e = te[2*t+k];
    int pos = atomicAdd(&cursor[e], 1);
    int s = off[e] + pos;
    tok_slot[s] = t;
    w_slot[s]   = tw[2*t+k];
    islot[2*t+k] = s;
  }
}

// ======== kernel B: gemm1 (8704 blocks) + dp-convert riders (1088) ======
// act stored NONTEMPORAL (R21): written once, read only after gemm1 completes;
// keeping it out of L2/L3 protects the L2-stationary gup16 + x16 panels.
__global__ __launch_bounds__(256, 2) void moe_gemm1_f16(
    const _Float16* __restrict__ x16, const _Float16* __restrict__ gup16,
    const int* __restrict__ iws, _Float16* __restrict__ act,
    const float* __restrict__ dp, _Float16* __restrict__ dp16)
{
  int bidr = blockIdx.x;
  int grp = bidr / 9, rem = bidr - grp * 9;
  if (rem == 8) {
    const int n8d = NE*NH*NI/8;
    int stride = 1088 * 256;
    for (int i = grp * 256 + threadIdx.x; i < n8d; i += stride) {
      const f32x4* p = (const f32x4*)(dp + (size_t)i * 8);
      f32x4 a = __builtin_nontemporal_load(p);
      f32x4 b = __builtin_nontemporal_load(p + 1);
      *(half8*)(dp16 + (size_t)i * 8) = pack_half8v(a, b);
    }
    return;
  }
  int bid = grp * 8 + rem;       // 0..8703

  const int* cnt = iws; const int* off = iws + 8; const int* mbc = iws + 25;
  const int* tok_slot = iws + 64 + NT*4;
  int mb  = bid >> 6;
  int i0  = (bid & 63) << 6;
  if (mb >= mbc[NE]) return;
  int e = 0;
  while (mb >= mbc[e+1]) ++e;
  int mloc  = mb - mbc[e];
  int row0  = off[e] + mloc * BM;
  int nrows = cnt[e] - mloc * BM; if (nrows > BM) nrows = BM;

  __shared__ __align__(16) _Float16 Al [3][BM * BK];
  __shared__ __align__(16) _Float16 Bgl[3][64 * BK];
  __shared__ __align__(16) _Float16 Bul[3][64 * BK];   // 48 KB -> 3 blocks/CU

  int tid = threadIdx.x, wid = tid >> 6, lane = tid & 63;
  int sr0 = wid*16 + (lane >> 2);
  int sr1 = 64 + sr0;
  int slot = lane & 3;
  int ks0 = (slot ^ ((sr0 >> 1) & 3)) * 8;
  int ks1 = (slot ^ ((sr1 >> 1) & 3)) * 8;

  int tok0 = tok_slot[row0 + (sr0 < nrows ? sr0 : 0)];
  int tok1 = tok_slot[row0 + (sr1 < nrows ? sr1 : 0)];
  const _Float16* pA0 = x16 + (size_t)tok0 * NH + ks0;
  const _Float16* pA1 = x16 + (size_t)tok1 * NH + ks1;
  const _Float16* pBg = gup16 + ((size_t)e*2*NI + i0 + sr0) * NH + ks0;
  const _Float16* pBu = pBg + (size_t)NI * NH;

  int wr = (wid >> 1) * 64, wc = (wid & 1) * 32;
  int fr = lane & 15, fq = lane >> 4;

  f32x4 accG[4][2] = {};
  f32x4 accU[4][2] = {};

  _Float16 *A0 = &Al[0][0], *A1 = &Al[1][0], *A2 = &Al[2][0];
  _Float16 *G0 = &Bgl[0][0], *G1 = &Bgl[1][0], *G2 = &Bgl[2][0];
  _Float16 *U0 = &Bul[0][0], *U1 = &Bul[1][0], *U2 = &Bul[2][0];

#define STAGE1(Ab, Gb, Ub, kk) do { \
    gload16(pA0 + (kk), (Ab) + wid*512); \
    gload16(pA1 + (kk), (Ab) + (4+wid)*512); \
    gload16(pBg + (kk), (Gb) + wid*512); \
    gload16(pBu + (kk), (Ub) + wid*512); \
  } while (0)

#define COMPUTE1(Ab, Gb, Ub) do { \
    half8 aF[4]; \
    _Pragma("unroll") \
    for (int m = 0; m < 4; ++m) { \
      int r = wr + m*16 + fr; \
      aF[m] = *(const half8*)((Ab) + r*BK + ((fq ^ ((r>>1)&3)) * 8)); \
    } \
    __builtin_amdgcn_s_setprio(1); \
    _Pragma("unroll") \
    for (int n = 0; n < 2; ++n) { \
      int rb = wc + n*16 + fr; \
      int bo = rb*BK + ((fq ^ ((rb>>1)&3)) * 8); \
      half8 bg = *(const half8*)((Gb) + bo); \
      half8 bu = *(const half8*)((Ub) + bo); \
      _Pragma("unroll") \
      for (int m = 0; m < 4; ++m) \
        accG[m][n] = __builtin_amdgcn_mfma_f32_16x16x32_f16(aF[m], bg, accG[m][n], 0, 0, 0); \
      _Pragma("unroll") \
      for (int m = 0; m < 4; ++m) \
        accU[m][n] = __builtin_amdgcn_mfma_f32_16x16x32_f16(aF[m], bu, accU[m][n], 0, 0, 0); \
    } \
    __builtin_amdgcn_s_setprio(0); \
  } while (0)

#define ROT1() do { _Float16* t_; \
    t_ = A0; A0 = A1; A1 = A2; A2 = t_; \
    t_ = G0; G0 = G1; G1 = G2; G2 = t_; \
    t_ = U0; U0 = U1; U1 = U2; U2 = t_; } while (0)

  STAGE1(A0, G0, U0, 0);
  STAGE1(A1, G1, U1, BK);

  for (int k0 = 0; k0 + 2*BK < NH; k0 += BK) {
    PIPE_WAIT(4);
    PIPE_BAR();
    STAGE1(A2, G2, U2, k0 + 2*BK);
    COMPUTE1(A0, G0, U0);
    ROT1();
  }
  PIPE_WAIT(4);
  PIPE_BAR();
  COMPUTE1(A0, G0, U0);
  ROT1();
  PIPE_WAIT(0);
  PIPE_BAR();
  COMPUTE1(A0, G0, U0);

#undef STAGE1
#undef COMPUTE1
#undef ROT1

  #pragma unroll
  for (int m = 0; m < 4; ++m) {
    #pragma unroll
    for (int j = 0; j < 4; ++j) {
      int rl = wr + m*16 + fq*4 + j;
      if (rl < nrows) {
        _Float16* dst = act + (size_t)(row0 + rl) * NI + i0 + wc + fr;
        #pragma unroll
        for (int n = 0; n < 2; ++n) {
          float g = accG[m][n][j], u = accU[m][n][j];
          float a = (g / (1.f + __expf(-g))) * u;
          __builtin_nontemporal_store((_Float16)a, dst + n*16);
        }
      }
    }
  }
}

// ======== gemm2 (R19 champion): 3-stage counted-vmcnt, 128x128, y-write =====
__global__ __launch_bounds__(256, 2) void moe_gemm2_f16(
    const _Float16* __restrict__ act, const _Float16* __restrict__ dp16,
    const int* __restrict__ iws, float* __restrict__ y)
{
  const int* cnt = iws; const int* off = iws + 8; const int* mbc = iws + 25;
  const float* w_slot = (const float*)(iws + 64 + NT*6);
  int bid = blockIdx.x;
  int mb  = ((bid >> 6) << 3) | (bid & 7);   // mb-window decode (R13)
  int h0  = ((bid >> 3) & 7) << 7;           // 8 h-slices of 128
  if (mb >= mbc[NE]) return;
  int e = 0;
  while (mb >= mbc[e+1]) ++e;
  int mloc  = mb - mbc[e];
  int row0  = off[e] + mloc * BM;
  int nrows = cnt[e] - mloc * BM; if (nrows > BM) nrows = BM;

  __shared__ __align__(16) _Float16 Al[3][BM  * BK];
  __shared__ __align__(16) _Float16 Bl[3][128 * BK];   // 48 KB -> 3 blocks/CU

  int tid = threadIdx.x, wid = tid >> 6, lane = tid & 63;
  int sr0 = wid*16 + (lane >> 2);
  int sr1 = 64 + sr0;
  int slot = lane & 3;
  int ks0 = (slot ^ ((sr0 >> 1) & 3)) * 8;
  int ks1 = (slot ^ ((sr1 >> 1) & 3)) * 8;

  const _Float16* pA0 = act + (size_t)(row0 + (sr0 < nrows ? sr0 : 0)) * NI + ks0;
  const _Float16* pA1 = act + (size_t)(row0 + (sr1 < nrows ? sr1 : 0)) * NI + ks1;
  const _Float16* pB0 = dp16 + ((size_t)e*NH + h0 + sr0) * NI + ks0;
  const _Float16* pB1 = dp16 + ((size_t)e*NH + h0 + sr1) * NI + ks1;

  int wr = (wid >> 1) * 64, wc = (wid & 1) * 64;
  int fr = lane & 15, fq = lane >> 4;

  f32x4 acc[4][4] = {};

  _Float16 *A0 = &Al[0][0], *A1 = &Al[1][0], *A2 = &Al[2][0];
  _Float16 *B0 = &Bl[0][0], *B1 = &Bl[1][0], *B2 = &Bl[2][0];

#define STAGE2(Ab, Bb, kk) do { \
    gload16(pA0 + (kk), (Ab) + wid*512); \
    gload16(pA1 + (kk), (Ab) + (4+wid)*512); \
    gload16(pB0 + (kk), (Bb) + wid*512); \
    gload16(pB1 + (kk), (Bb) + (4+wid)*512); \
  } while (0)

#define COMPUTE2(Ab, Bb) do { \
    half8 aF[4]; \
    _Pragma("unroll") \
    for (int m = 0; m < 4; ++m) { \
      int r = wr + m*16 + fr; \
      aF[m] = *(const half8*)((Ab) + r*BK + ((fq ^ ((r>>1)&3)) * 8)); \
    } \
    __builtin_amdgcn_s_setprio(1); \
    _Pragma("unroll") \
    for (int n = 0; n < 4; ++n) { \
      int rb = wc + n*16 + fr; \
      half8 b = *(const half8*)((Bb) + rb*BK + ((fq ^ ((rb>>1)&3)) * 8)); \
      _Pragma("unroll") \
      for (int m = 0; m < 4; ++m) \
        acc[m][n] = __builtin_amdgcn_mfma_f32_16x16x32_f16(aF[m], b, acc[m][n], 0, 0, 0); \
    } \
    __builtin_amdgcn_s_setprio(0); \
  } while (0)

#define ROT2() do { _Float16* t_; \
    t_ = A0; A0 = A1; A1 = A2; A2 = t_; \
    t_ = B0; B0 = B1; B1 = B2; B2 = t_; } while (0)

  STAGE2(A0, B0, 0);
  STAGE2(A1, B1, BK);

  for (int k0 = 0; k0 + 2*BK < NI; k0 += BK) {
    PIPE_WAIT(4);
    PIPE_BAR();
    STAGE2(A2, B2, k0 + 2*BK);
    COMPUTE2(A0, B0);
    ROT2();
  }
  PIPE_WAIT(4);
  PIPE_BAR();
  COMPUTE2(A0, B0);
  ROT2();
  PIPE_WAIT(0);
  PIPE_BAR();
  COMPUTE2(A0, B0);

#undef STAGE2
#undef COMPUTE2
#undef ROT2

  // epilogue: y[slot][h0+col] = wgt * acc (exclusive row ownership, no atomics)
  #pragma unroll
  for (int m = 0; m < 4; ++m) {
    #pragma unroll
    for (int j = 0; j < 4; ++j) {
      int rl = wr + m*16 + fq*4 + j;
      if (rl < nrows) {
        int slotr = row0 + rl;
        float wgt = w_slot[slotr];
        float* dst = y + (size_t)slotr * NH + h0 + wc + fr;
        #pragma unroll
        for (int n = 0; n < 4; ++n)
          dst[n*16] = acc[m][n][j] * wgt;
      }
    }
  }
}

// ======== combine: out[t] = y[islot0(t)] + y[islot1(t)] (NT loads) ========
__global__ __launch_bounds__(256) void moe_combine(
    const float* __restrict__ y, const int* __restrict__ iws,
    float* __restrict__ out)
{
  const int* islot = iws + 64 + NT*8;
  int t = blockIdx.x;
  int s0 = islot[2*t], s1 = islot[2*t+1];
  const f32x4* y0 = (const f32x4*)(y + (size_t)s0 * NH);
  const f32x4* y1 = (const f32x4*)(y + (size_t)s1 * NH);
  f32x4* o = (f32x4*)(out + (size_t)t * NH);
  int i = threadIdx.x;           // 256 threads x f32x4 = 1024 elems
  f32x4 a = __builtin_nontemporal_load(y0 + i);
  f32x4 b = __builtin_nontemporal_load(y1 + i);
  o[i] = a + b;
}

extern "C" void kernel_launch(void* const* d_in, const int* in_sizes, int n_in,
                              void* d_out, int out_size, void* d_ws, size_t ws_size,
                              hipStream_t stream) {
  const float* x   = (const float*)d_in[0];
  const float* rw  = (const float*)d_in[1];
  const float* gup = (const float*)d_in[2];
  const float* dp  = (const float*)d_in[3];
  float* out = (float*)d_out;
  int* iws = (int*)d_ws;
  _Float16* x16   = (_Float16*)((char*)d_ws + OFF_X16);
  _Float16* act   = (_Float16*)((char*)d_ws + OFF_ACT);
  _Float16* gup16 = (_Float16*)((char*)d_ws + OFF_GUP16);
  _Float16* dp16  = (_Float16*)((char*)d_ws + OFF_DP16);
  // y_slots overlays gup16's region (gemm1 done before gemm2 writes it)
  float* y = (float*)((char*)d_ws + OFF_GUP16);

  hipMemsetAsync(d_ws, 0, 512, stream);

  // A: router (2048) + gup convert (4096) fused
  conv_router<<<6144, 256, 0, stream>>>(x, rw, iws, x16, gup, gup16);
  moe_scan<<<1, 64, 0, stream>>>(iws);
  moe_fill<<<NT / 256, 256, 0, stream>>>(iws);

  // B: gemm1 (8704) + dp-convert riders (1088) interleaved every 9th bid
  moe_gemm1_f16<<<9792, 256, 0, stream>>>(x16, gup16, iws, act, dp, dp16);
  // gemm2: mb-window permuted grid, 136 x 8 = 1088; writes y_slots rows
  moe_gemm2_f16<<<(NT * 2 / BM + NE) * (NH / 128), 256, 0, stream>>>(act, dp16, iws, y);
  moe_combine<<<NT, 256, 0, stream>>>(y, iws, out);
}